// Round 1
// baseline (6341.991 us; speedup 1.0000x reference)
//
#include <hip/hip_runtime.h>

#define S_LEN 512
#define B_SZ  32
#define H_SZ  1024
#define NG    4096      // 4H
#define K_SZ  1024
#define GWG   128       // persistent workgroups

typedef __attribute__((ext_vector_type(8))) short short8;
typedef __attribute__((ext_vector_type(4))) float floatx4;
typedef __attribute__((ext_vector_type(4))) unsigned short ushort4v;

// ---------------- helpers ----------------
__device__ __forceinline__ unsigned short f2bf(float f){
  unsigned u = __float_as_uint(f);
  u += 0x7fffu + ((u >> 16) & 1u);     // RNE; inputs are finite/normal
  return (unsigned short)(u >> 16);
}
__device__ __forceinline__ float sigm(float x){ return 1.f / (1.f + __expf(-x)); }
__device__ __forceinline__ float tanh_f(float x){
  float ax = fabsf(x);
  float e = __expf(-2.f * ax);
  float r = (1.f - e) / (1.f + e);
  return copysignf(r, x);
}

// ---------------- fp32 -> bf16 conversion ----------------
__global__ __launch_bounds__(256) void cvt_bf16(const float* __restrict__ s,
                                                unsigned short* __restrict__ d, int n){
  int i = (blockIdx.x * 256 + threadIdx.x) * 4;
  if (i < n){
    float4 v = *(const float4*)(s + i);
    ushort4v o; o.x = f2bf(v.x); o.y = f2bf(v.y); o.z = f2bf(v.z); o.w = f2bf(v.w);
    *(ushort4v*)(d + i) = o;
  }
}

// h0 -> bf16 exchange buffer 0, and zero the barrier counter (ws is poisoned each launch)
__global__ __launch_bounds__(256) void cvt_h0(const float* __restrict__ s,
                                              unsigned short* __restrict__ d,
                                              unsigned* __restrict__ cnt){
  int i = (blockIdx.x * 256 + threadIdx.x) * 4;   // grid covers exactly 32768
  float4 v = *(const float4*)(s + i);
  ushort4v o; o.x = f2bf(v.x); o.y = f2bf(v.y); o.z = f2bf(v.z); o.w = f2bf(v.w);
  *(ushort4v*)(d + i) = o;
  if (blockIdx.x == 0 && threadIdx.x == 0) *cnt = 0u;
}

// ---------------- Phase A: gates_pre[M=16384, 4096] = Xb @ Ub^T  (m97 structure) ----------------
// A: [M,K] bf16 row-major; Bm: [N,K] bf16 row-major (i.e. U as stored); C: [M,N] fp32
__global__ __launch_bounds__(256) void gemm_xu(const short* __restrict__ A,
                                               const short* __restrict__ Bm,
                                               float* __restrict__ C){
  __shared__ short As[128 * 32];
  __shared__ short Bs[128 * 32];
  const int tid = threadIdx.x;
  const int wave = tid >> 6, lane = tid & 63;
  const int bm = blockIdx.x, bn = blockIdx.y;
  const int wm = (wave >> 1) * 64, wn = (wave & 1) * 64;
  const int ml = lane & 15, kg = lane >> 4;
  floatx4 acc[4][4] = {};
  const short* Abase = A + (size_t)bm * 128 * K_SZ;
  const short* Bbase = Bm + (size_t)bn * 128 * K_SZ;
  for (int k0 = 0; k0 < K_SZ; k0 += 32){
#pragma unroll
    for (int i = 0; i < 2; ++i){
      int r0 = (wave * 2 + i) * 16;             // wave-uniform LDS base: 16 rows x 64B = 1024B
      int row = r0 + (lane >> 2);
      int cof = (lane & 3) * 8;                 // shorts
      __builtin_amdgcn_global_load_lds(
        (const __attribute__((address_space(1))) void*)(Abase + (size_t)row * K_SZ + k0 + cof),
        (__attribute__((address_space(3))) void*)(As + r0 * 32), 16, 0, 0);
      __builtin_amdgcn_global_load_lds(
        (const __attribute__((address_space(1))) void*)(Bbase + (size_t)row * K_SZ + k0 + cof),
        (__attribute__((address_space(3))) void*)(Bs + r0 * 32), 16, 0, 0);
    }
    __syncthreads();
    short8 af[4], bf[4];
#pragma unroll
    for (int mt = 0; mt < 4; ++mt) af[mt] = *(const short8*)&As[(wm + mt * 16 + ml) * 32 + kg * 8];
#pragma unroll
    for (int nt = 0; nt < 4; ++nt) bf[nt] = *(const short8*)&Bs[(wn + nt * 16 + ml) * 32 + kg * 8];
#pragma unroll
    for (int mt = 0; mt < 4; ++mt)
#pragma unroll
      for (int nt = 0; nt < 4; ++nt)
        acc[mt][nt] = __builtin_amdgcn_mfma_f32_16x16x32_bf16(af[mt], bf[nt], acc[mt][nt], 0, 0, 0);
    __syncthreads();
  }
#pragma unroll
  for (int mt = 0; mt < 4; ++mt){
#pragma unroll
    for (int nt = 0; nt < 4; ++nt){
      int row0 = bm * 128 + wm + mt * 16 + kg * 4;
      int col  = bn * 128 + wn + nt * 16 + ml;
#pragma unroll
      for (int r = 0; r < 4; ++r)
        C[(size_t)(row0 + r) * NG + col] = acc[mt][nt][r];   // C[m][n]: row=(lane>>4)*4+r, col=lane&15 (m89-verified)
    }
  }
}

// ---------------- Phase B: persistent LSTM recurrence ----------------
// 128 WGs, 1/CU. WG wg owns hidden units j0..j0+7 (all 4 gates = 32 rows of V) for all 32 batches.
// LDS: Vs 32x(1024+8) bf16, hS 32x(1024+8) bf16 (pad 16B -> 2-way bank alias only, free per m136)
#define LPAD 1032
__global__ __launch_bounds__(256) void lstm_rec(const float* __restrict__ gates_pre,
                                                const short* __restrict__ Vb,
                                                const float* __restrict__ bih,
                                                const float* __restrict__ bhh,
                                                const float* __restrict__ c0,
                                                unsigned short* __restrict__ hb0,
                                                unsigned short* __restrict__ hb1,
                                                unsigned* __restrict__ cnt,
                                                float* __restrict__ out){
  __shared__ short Vs[32 * LPAD];
  __shared__ short hS[32 * LPAD];
  __shared__ float gatesS[32 * 32];
  __shared__ float biasS[32];
  __shared__ float cS[256];
  const int tid = threadIdx.x;
  const int wave = tid >> 6, lane = tid & 63;
  const int ml = lane & 15, lg = lane >> 4;
  const int wg = blockIdx.x;
  const int j0 = wg * 8;
  const int mt = wave >> 1, nt = wave & 1;     // wave -> 16x16 tile of the 32x32 gate slice

  // ---- init: V slice, bias slice, c slice ----
#pragma unroll
  for (int i = 0; i < 16; ++i){
    int e = i * 2048 + tid * 8;                // 32768 shorts total
    int rr = e >> 10, cc = e & 1023;           // rr = g*8 + rloc
    int g = rr >> 3, rloc = rr & 7;
    const short* src = Vb + (size_t)(g * 1024 + j0 + rloc) * 1024 + cc;
    *(short8*)&Vs[rr * LPAD + cc] = *(const short8*)src;
  }
  if (tid < 32){
    int g = tid >> 3, jj = tid & 7;
    int gc = g * 1024 + j0 + jj;
    biasS[tid] = bih[gc] + bhh[gc];
  }
  { int b = tid >> 3, jj = tid & 7;
    cS[tid] = c0[b * 1024 + j0 + jj]; }
  __syncthreads();

  const size_t SBH = (size_t)S_LEN * B_SZ * H_SZ;
  const size_t BH  = (size_t)B_SZ * H_SZ;
  float* out_h  = out;
  float* out_hf = out + SBH;
  float* out_cf = out + SBH + BH;
  float* out_h2 = out + SBH + 2 * BH;
  float* out_c  = out + 2 * SBH + 2 * BH;

  for (int t = 0; t < S_LEN; ++t){
    // acc init = gates_pre slice (x@U^T), loaded early to overlap staging
    const int c_sl = nt * 16 + ml;
    const int gcol = (c_sl >> 3) * 1024 + j0 + (c_sl & 7);
    floatx4 acc0, acc1;
    {
      const float* gp = gates_pre + (size_t)(t * 32 + mt * 16 + lg * 4) * NG + gcol;
#pragma unroll
      for (int r = 0; r < 4; ++r) acc0[r] = gp[(size_t)r * NG];
      acc1[0] = 0.f; acc1[1] = 0.f; acc1[2] = 0.f; acc1[3] = 0.f;
    }
    // stage full h (bf16) into LDS, coalesced 16B/lane
    const unsigned short* hb = (t & 1) ? hb1 : hb0;
#pragma unroll
    for (int i = 0; i < 16; ++i){
      int e = i * 2048 + tid * 8;
      int rr = e >> 10, cc = e & 1023;
      *(short8*)&hS[rr * LPAD + cc] = *(const short8*)(hb + e);
    }
    __syncthreads();
    // K loop: gates[b][c] += sum_k h[b][k] * Vs[c][k]; 2 indep acc chains for ILP
    const int abase = (mt * 16 + ml) * LPAD + lg * 8;
    const int bbase = (nt * 16 + ml) * LPAD + lg * 8;
#pragma unroll
    for (int kk = 0; kk < 32; kk += 2){
      short8 a0 = *(const short8*)&hS[abase + kk * 32];
      short8 b0 = *(const short8*)&Vs[bbase + kk * 32];
      short8 a1 = *(const short8*)&hS[abase + kk * 32 + 32];
      short8 b1 = *(const short8*)&Vs[bbase + kk * 32 + 32];
      acc0 = __builtin_amdgcn_mfma_f32_16x16x32_bf16(a0, b0, acc0, 0, 0, 0);
      acc1 = __builtin_amdgcn_mfma_f32_16x16x32_bf16(a1, b1, acc1, 0, 0, 0);
    }
    acc0 += acc1;
#pragma unroll
    for (int r = 0; r < 4; ++r)
      gatesS[(mt * 16 + lg * 4 + r) * 32 + c_sl] = acc0[r];
    __syncthreads();
    // cell update: one (b, jj) per thread
    {
      int b = tid >> 3, jj = tid & 7;
      float gi = gatesS[b * 32 + jj]      + biasS[jj];
      float gf = gatesS[b * 32 + 8 + jj]  + biasS[8 + jj];
      float gg = gatesS[b * 32 + 16 + jj] + biasS[16 + jj];
      float go = gatesS[b * 32 + 24 + jj] + biasS[24 + jj];
      float iv = sigm(gi), fv = sigm(gf), gv = tanh_f(gg), ov = sigm(go);
      float cv = fv * cS[tid] + iv * gv;
      cS[tid] = cv;
      float hv = ov * tanh_f(cv);
      size_t o = (size_t)t * BH + (size_t)b * H_SZ + (size_t)(j0 + jj);
      out_h[o] = hv; out_h2[o] = hv; out_c[o] = cv;
      if (t == S_LEN - 1){
        out_hf[b * H_SZ + j0 + jj] = hv;
        out_cf[b * H_SZ + j0 + jj] = cv;
      }
      unsigned short* hw = (t & 1) ? hb0 : hb1;
      hw[b * 1024 + j0 + jj] = f2bf(hv);
    }
    // device-scope barrier (monotonic counter). Max inter-WG skew = 1 step -> double buffer is safe.
    if (t < S_LEN - 1){
      __syncthreads();   // drains each wave's vmem stores (vmcnt(0) before s_barrier)
      if (tid == 0){
        __hip_atomic_fetch_add(cnt, 1u, __ATOMIC_RELEASE, __HIP_MEMORY_SCOPE_AGENT);
        unsigned target = (unsigned)GWG * (unsigned)(t + 1);
        while (__hip_atomic_load(cnt, __ATOMIC_RELAXED, __HIP_MEMORY_SCOPE_AGENT) < target)
          __builtin_amdgcn_s_sleep(1);
        __threadfence();   // acquire: invalidate L1/L2 before re-reading h
      }
      __syncthreads();
    }
  }
}

// ---------------- launch ----------------
// ws layout (bytes)
#define WS_CNT 0
#define WS_H0  4096
#define WS_H1  (4096 + 65536)
#define WS_XB  (4096 + 2 * 65536)          // X bf16: 32 MB
#define WS_UB  (WS_XB + 33554432)          // U bf16: 8 MB
#define WS_VB  (WS_UB + 8388608)           // V bf16: 8 MB
#define WS_GP  (WS_VB + 8388608)           // gates_pre fp32: 268.4 MB

extern "C" void kernel_launch(void* const* d_in, const int* in_sizes, int n_in,
                              void* d_out, int out_size, void* d_ws, size_t ws_size,
                              hipStream_t stream) {
  const float* X   = (const float*)d_in[0];   // [512,32,1024]
  const float* h0  = (const float*)d_in[1];   // [32,1024]
  const float* c0  = (const float*)d_in[2];   // [32,1024]
  const float* U   = (const float*)d_in[3];   // [4096,1024]
  const float* V   = (const float*)d_in[4];   // [4096,1024]
  const float* bih = (const float*)d_in[5];
  const float* bhh = (const float*)d_in[6];
  float* out = (float*)d_out;
  char* ws = (char*)d_ws;

  unsigned* cnt        = (unsigned*)(ws + WS_CNT);
  unsigned short* hb0  = (unsigned short*)(ws + WS_H0);
  unsigned short* hb1  = (unsigned short*)(ws + WS_H1);
  unsigned short* Xb   = (unsigned short*)(ws + WS_XB);
  unsigned short* Ub   = (unsigned short*)(ws + WS_UB);
  unsigned short* Vb   = (unsigned short*)(ws + WS_VB);
  float* gates         = (float*)(ws + WS_GP);

  cvt_bf16<<<dim3(16384), 256, 0, stream>>>(X, Xb, 16777216);
  cvt_bf16<<<dim3(4096),  256, 0, stream>>>(U, Ub, 4194304);
  cvt_bf16<<<dim3(4096),  256, 0, stream>>>(V, Vb, 4194304);
  cvt_h0  <<<dim3(32),    256, 0, stream>>>(h0, hb0, cnt);
  gemm_xu <<<dim3(128, 32), 256, 0, stream>>>((const short*)Xb, (const short*)Ub, gates);
  lstm_rec<<<dim3(GWG),   256, 0, stream>>>(gates, (const short*)Vb, bih, bhh, c0,
                                            hb0, hb1, cnt, out);
}

// Round 2
// 2746.204 us; speedup vs baseline: 2.3094x; 2.3094x over previous
//
#include <hip/hip_runtime.h>

#define S_LEN 512
#define B_SZ  32
#define H_SZ  1024
#define NG    4096      // 4H
#define K_SZ  1024
#define GWG   128       // persistent workgroups

typedef __attribute__((ext_vector_type(8))) short short8;
typedef __attribute__((ext_vector_type(4))) float floatx4;
typedef __attribute__((ext_vector_type(4))) unsigned short ushort4v;

// ---------------- helpers ----------------
__device__ __forceinline__ unsigned short f2bf(float f){
  unsigned u = __float_as_uint(f);
  u += 0x7fffu + ((u >> 16) & 1u);     // RNE; inputs are finite/normal
  return (unsigned short)(u >> 16);
}
__device__ __forceinline__ float bf2f(unsigned short u){
  return __uint_as_float(((unsigned)u) << 16);
}
__device__ __forceinline__ float sigm(float x){ return 1.f / (1.f + __expf(-x)); }
__device__ __forceinline__ float tanh_f(float x){
  float ax = fabsf(x);
  float e = __expf(-2.f * ax);
  float r = (1.f - e) / (1.f + e);
  return copysignf(r, x);
}

// ---------------- fp32 -> bf16 conversion ----------------
__global__ __launch_bounds__(256) void cvt_bf16(const float* __restrict__ s,
                                                unsigned short* __restrict__ d, int n){
  int i = (blockIdx.x * 256 + threadIdx.x) * 4;
  if (i < n){
    float4 v = *(const float4*)(s + i);
    ushort4v o; o.x = f2bf(v.x); o.y = f2bf(v.y); o.z = f2bf(v.z); o.w = f2bf(v.w);
    *(ushort4v*)(d + i) = o;
  }
}

// h0 -> bf16 into hist[0], and zero the 128 arrival flags (ws re-poisoned each launch)
__global__ __launch_bounds__(256) void cvt_h0(const float* __restrict__ s,
                                              unsigned short* __restrict__ d,
                                              unsigned* __restrict__ flags){
  int i = (blockIdx.x * 256 + threadIdx.x) * 4;   // grid covers exactly 32768
  float4 v = *(const float4*)(s + i);
  ushort4v o; o.x = f2bf(v.x); o.y = f2bf(v.y); o.z = f2bf(v.z); o.w = f2bf(v.w);
  *(ushort4v*)(d + i) = o;
  if (blockIdx.x == 0){ flags[threadIdx.x] = 0u; flags[256 + threadIdx.x] = 0u; }
}

// ---------------- Phase A: gates_pre[M=16384, 4096] = Xb @ Ub^T (bf16 out) ----------------
__global__ __launch_bounds__(256) void gemm_xu(const short* __restrict__ A,
                                               const short* __restrict__ Bm,
                                               unsigned short* __restrict__ C){
  __shared__ short As[128 * 32];
  __shared__ short Bs[128 * 32];
  const int tid = threadIdx.x;
  const int wave = tid >> 6, lane = tid & 63;
  const int bm = blockIdx.x, bn = blockIdx.y;
  const int wm = (wave >> 1) * 64, wn = (wave & 1) * 64;
  const int ml = lane & 15, kg = lane >> 4;
  floatx4 acc[4][4] = {};
  const short* Abase = A + (size_t)bm * 128 * K_SZ;
  const short* Bbase = Bm + (size_t)bn * 128 * K_SZ;
  for (int k0 = 0; k0 < K_SZ; k0 += 32){
#pragma unroll
    for (int i = 0; i < 2; ++i){
      int r0 = (wave * 2 + i) * 16;
      int row = r0 + (lane >> 2);
      int cof = (lane & 3) * 8;
      __builtin_amdgcn_global_load_lds(
        (const __attribute__((address_space(1))) void*)(Abase + (size_t)row * K_SZ + k0 + cof),
        (__attribute__((address_space(3))) void*)(As + r0 * 32), 16, 0, 0);
      __builtin_amdgcn_global_load_lds(
        (const __attribute__((address_space(1))) void*)(Bbase + (size_t)row * K_SZ + k0 + cof),
        (__attribute__((address_space(3))) void*)(Bs + r0 * 32), 16, 0, 0);
    }
    __syncthreads();
    short8 af[4], bf[4];
#pragma unroll
    for (int mt = 0; mt < 4; ++mt) af[mt] = *(const short8*)&As[(wm + mt * 16 + ml) * 32 + kg * 8];
#pragma unroll
    for (int nt = 0; nt < 4; ++nt) bf[nt] = *(const short8*)&Bs[(wn + nt * 16 + ml) * 32 + kg * 8];
#pragma unroll
    for (int mt = 0; mt < 4; ++mt)
#pragma unroll
      for (int nt = 0; nt < 4; ++nt)
        acc[mt][nt] = __builtin_amdgcn_mfma_f32_16x16x32_bf16(af[mt], bf[nt], acc[mt][nt], 0, 0, 0);
    __syncthreads();
  }
#pragma unroll
  for (int mt = 0; mt < 4; ++mt){
#pragma unroll
    for (int nt = 0; nt < 4; ++nt){
      int row0 = bm * 128 + wm + mt * 16 + kg * 4;
      int col  = bn * 128 + wn + nt * 16 + ml;
#pragma unroll
      for (int r = 0; r < 4; ++r)
        C[(size_t)(row0 + r) * NG + col] = f2bf(acc[mt][nt][r]);
    }
  }
}

// ---------------- Phase B: persistent LSTM recurrence ----------------
// 128 WGs, 1/CU. WG wg owns hidden units j0..j0+7 (4 gates = 32 rows of V), all 32 batches.
// No fences in the loop: h exchanged via sc0|sc1 (L3-coherent) paths; unique h buffer per step.
#define LPAD 1032
#define GPADW 36   // gatesS row stride (floats): 2-way max bank alias (free per m136)
__global__ __launch_bounds__(256) void lstm_rec(const unsigned short* __restrict__ gates_pre,
                                                const short* __restrict__ Vb,
                                                const float* __restrict__ bih,
                                                const float* __restrict__ bhh,
                                                const float* __restrict__ c0,
                                                unsigned short* __restrict__ hh,   // hist: 513 x 32768 bf16
                                                unsigned* __restrict__ flags,      // 128 x 4 uints (16B apart)
                                                float* __restrict__ out){
  __shared__ short Vs[32 * LPAD];
  __shared__ short hS[32 * LPAD];
  __shared__ float gatesS[32 * GPADW];
  __shared__ unsigned short hsS[256];
  const int tid = threadIdx.x;
  const int wave = tid >> 6, lane = tid & 63;
  const int ml = lane & 15, lg = lane >> 4;
  const int wg = blockIdx.x;
  const int j0 = wg * 8;
  const int mt = wave >> 1, nt = wave & 1;     // wave -> 16x16 tile of the 32x32 gate slice

  // ---- init: V slice to LDS; bias + c to registers ----
#pragma unroll
  for (int i = 0; i < 16; ++i){
    int e = i * 2048 + tid * 8;                // 32768 shorts total
    int rr = e >> 10, cc = e & 1023;           // rr = g*8 + rloc
    int g = rr >> 3, rloc = rr & 7;
    const short* src = Vb + (size_t)(g * 1024 + j0 + rloc) * 1024 + cc;
    *(short8*)&Vs[rr * LPAD + cc] = *(const short8*)src;
  }
  const int b_own = tid >> 3, jj_own = tid & 7;
  float bias_i = bih[0 * 1024 + j0 + jj_own] + bhh[0 * 1024 + j0 + jj_own];
  float bias_f = bih[1 * 1024 + j0 + jj_own] + bhh[1 * 1024 + j0 + jj_own];
  float bias_g = bih[2 * 1024 + j0 + jj_own] + bhh[2 * 1024 + j0 + jj_own];
  float bias_o = bih[3 * 1024 + j0 + jj_own] + bhh[3 * 1024 + j0 + jj_own];
  float c_reg  = c0[b_own * 1024 + j0 + jj_own];
  __syncthreads();

  const size_t SBH = (size_t)S_LEN * B_SZ * H_SZ;
  const size_t BH  = (size_t)B_SZ * H_SZ;
  float* out_h  = out;
  float* out_hf = out + SBH;
  float* out_cf = out + SBH + BH;
  float* out_h2 = out + SBH + 2 * BH;
  float* out_c  = out + 2 * SBH + 2 * BH;

  // per-thread gates_pre fragment coords
  const int c_sl = nt * 16 + ml;                          // gate-slice column 0..31
  const int gcol = (c_sl >> 3) * 1024 + j0 + (c_sl & 7);  // column in 4096
  // prefetch gates_pre for t=0
  unsigned short gpr0, gpr1, gpr2, gpr3;
  {
    const unsigned short* gp = gates_pre + (size_t)(0 * 32 + mt * 16 + lg * 4) * NG + gcol;
    gpr0 = gp[0]; gpr1 = gp[NG]; gpr2 = gp[2 * (size_t)NG]; gpr3 = gp[3 * (size_t)NG];
  }

  for (int t = 0; t < S_LEN; ++t){
    // ---- wait for all WGs to have published h for step t (skip t=0: hist[0] from cvt_h0) ----
    if (t > 0){
      if (tid < 128){
        const unsigned* f = flags + tid * 4;
        while (__hip_atomic_load(f, __ATOMIC_RELAXED, __HIP_MEMORY_SCOPE_AGENT) < (unsigned)t)
          __builtin_amdgcn_s_sleep(1);
      }
      __syncthreads();
    }
    // ---- stage h(t) -> LDS, direct, L3-coherent (aux 17 = sc0|sc1), 16B/lane ----
    const unsigned short* hb = hh + (size_t)t * 32768;
#pragma unroll
    for (int i = 0; i < 16; ++i){
      int e_base = i * 2048 + wave * 512;       // wave-uniform
      int rr = e_base >> 10, cc0 = e_base & 1023;
      __builtin_amdgcn_global_load_lds(
        (const __attribute__((address_space(1))) void*)(hb + e_base + lane * 8),
        (__attribute__((address_space(3))) void*)(hS + rr * LPAD + cc0), 16, 0, 17);
    }
    // acc init from prefetched gates_pre (x@U^T)
    floatx4 acc0, acc1;
    acc0[0] = bf2f(gpr0); acc0[1] = bf2f(gpr1); acc0[2] = bf2f(gpr2); acc0[3] = bf2f(gpr3);
    acc1[0] = 0.f; acc1[1] = 0.f; acc1[2] = 0.f; acc1[3] = 0.f;
    __syncthreads();
    // ---- K loop: gates[b][c] += sum_k h[b][k] * V[c][k] ----
    const int abase = (mt * 16 + ml) * LPAD + lg * 8;
    const int bbase = (nt * 16 + ml) * LPAD + lg * 8;
#pragma unroll
    for (int kk = 0; kk < 32; kk += 2){
      short8 a0 = *(const short8*)&hS[abase + kk * 32];
      short8 b0 = *(const short8*)&Vs[bbase + kk * 32];
      short8 a1 = *(const short8*)&hS[abase + kk * 32 + 32];
      short8 b1 = *(const short8*)&Vs[bbase + kk * 32 + 32];
      acc0 = __builtin_amdgcn_mfma_f32_16x16x32_bf16(a0, b0, acc0, 0, 0, 0);
      acc1 = __builtin_amdgcn_mfma_f32_16x16x32_bf16(a1, b1, acc1, 0, 0, 0);
    }
    acc0 += acc1;
#pragma unroll
    for (int r = 0; r < 4; ++r)
      gatesS[(mt * 16 + lg * 4 + r) * GPADW + c_sl] = acc0[r];
    __syncthreads();
    // ---- cell update: one (b, jj) per thread ----
    {
      float gi = gatesS[b_own * GPADW + jj_own]      + bias_i;
      float gf = gatesS[b_own * GPADW + 8 + jj_own]  + bias_f;
      float gg = gatesS[b_own * GPADW + 16 + jj_own] + bias_g;
      float go = gatesS[b_own * GPADW + 24 + jj_own] + bias_o;
      float iv = sigm(gi), fv = sigm(gf), gv = tanh_f(gg), ov = sigm(go);
      float cv = fv * c_reg + iv * gv;
      c_reg = cv;
      float hv = ov * tanh_f(cv);
      size_t o = (size_t)t * BH + (size_t)b_own * H_SZ + (size_t)(j0 + jj_own);
      __builtin_nontemporal_store(hv, &out_h[o]);
      __builtin_nontemporal_store(hv, &out_h2[o]);
      __builtin_nontemporal_store(cv, &out_c[o]);
      if (t == S_LEN - 1){
        out_hf[b_own * H_SZ + j0 + jj_own] = hv;
        out_cf[b_own * H_SZ + j0 + jj_own] = cv;
      }
      hsS[tid] = f2bf(hv);
    }
    __syncthreads();
    // ---- publish h slice (wave 0 only): sc0|sc1 stores -> L3, then flag ----
    if (t + 1 < S_LEN){
      if (tid < 64){
        unsigned long long v = ((const unsigned long long*)hsS)[tid];  // ushorts tid*4..tid*4+3
        int b = tid >> 1, half = tid & 1;
        unsigned long long* dst =
          (unsigned long long*)(hh + (size_t)(t + 1) * 32768 + b * 1024 + j0 + half * 4);
        __hip_atomic_store(dst, v, __ATOMIC_RELAXED, __HIP_MEMORY_SCOPE_AGENT);
      }
      if (tid == 0){
        asm volatile("s_waitcnt vmcnt(0)" ::: "memory");   // h stores acked at L3 before flag
        __hip_atomic_store(flags + wg * 4, (unsigned)(t + 1),
                           __ATOMIC_RELAXED, __HIP_MEMORY_SCOPE_AGENT);
      }
      // prefetch gates_pre for t+1 (overlaps next poll)
      const unsigned short* gp = gates_pre + (size_t)((t + 1) * 32 + mt * 16 + lg * 4) * NG + gcol;
      gpr0 = gp[0]; gpr1 = gp[NG]; gpr2 = gp[2 * (size_t)NG]; gpr3 = gp[3 * (size_t)NG];
    }
  }
}

// ---------------- launch ----------------
// ws layout (bytes)
#define WS_FLG 0                                  // 128 flags, 16B apart (2 KB)
#define WS_HH  4096                               // h history: 513 * 64 KB = 33,619,968
#define WS_XB  (4096 + 513 * 65536)               // X bf16: 32 MB
#define WS_UB  (WS_XB + 33554432)                 // U bf16: 8 MB
#define WS_VB  (WS_UB + 8388608)                  // V bf16: 8 MB
#define WS_GP  (WS_VB + 8388608)                  // gates_pre bf16: 134.2 MB

extern "C" void kernel_launch(void* const* d_in, const int* in_sizes, int n_in,
                              void* d_out, int out_size, void* d_ws, size_t ws_size,
                              hipStream_t stream) {
  const float* X   = (const float*)d_in[0];   // [512,32,1024]
  const float* h0  = (const float*)d_in[1];   // [32,1024]
  const float* c0  = (const float*)d_in[2];   // [32,1024]
  const float* U   = (const float*)d_in[3];   // [4096,1024]
  const float* V   = (const float*)d_in[4];   // [4096,1024]
  const float* bih = (const float*)d_in[5];
  const float* bhh = (const float*)d_in[6];
  float* out = (float*)d_out;
  char* ws = (char*)d_ws;

  unsigned* flags      = (unsigned*)(ws + WS_FLG);
  unsigned short* hh   = (unsigned short*)(ws + WS_HH);
  unsigned short* Xb   = (unsigned short*)(ws + WS_XB);
  unsigned short* Ub   = (unsigned short*)(ws + WS_UB);
  unsigned short* Vb   = (unsigned short*)(ws + WS_VB);
  unsigned short* gates = (unsigned short*)(ws + WS_GP);

  cvt_bf16<<<dim3(16384), 256, 0, stream>>>(X, Xb, 16777216);
  cvt_bf16<<<dim3(4096),  256, 0, stream>>>(U, Ub, 4194304);
  cvt_bf16<<<dim3(4096),  256, 0, stream>>>(V, Vb, 4194304);
  cvt_h0  <<<dim3(32),    256, 0, stream>>>(h0, hh, flags);
  gemm_xu <<<dim3(128, 32), 256, 0, stream>>>((const short*)Xb, (const short*)Ub, gates);
  lstm_rec<<<dim3(GWG),   256, 0, stream>>>(gates, (const short*)Vb, bih, bhh, c0,
                                            hh, flags, out);
}